// Round 16
// baseline (85.354 us; speedup 1.0000x reference)
//
#include <hip/hip_runtime.h>
#include <hip/hip_bf16.h>
#include <stdint.h>

typedef _Float16 half8 __attribute__((ext_vector_type(8)));
typedef _Float16 half4 __attribute__((ext_vector_type(4)));
typedef __fp16 fp16x2 __attribute__((ext_vector_type(2)));
typedef float floatx4 __attribute__((ext_vector_type(4)));
typedef float floatx16 __attribute__((ext_vector_type(16)));

#define SCALE 0.14433756729740643f
#define LOG2E 1.4426950408889634f

// ws layout (bytes):
// Qswz f16 [64bh][32ntile][4t][64lane][8]  off 0         fragment-major Q (raw; GN folded in attn)
// Kswz f16 [64bh][32win][4t][64lane][8]    off 8388608   fragment-major K
// Vswz f16 [64bh][32win][2c][2kc][64][8]   off 16777216  fragment-major V
// gnpart f32 [8b][8h][16nblk][2]           off 25165824  per-(head,nblk) GN partials
// Yf   f16 [8][384][1024]                  off 26214400  scrambled pre-proj (flat order, f16)
// Xt   f16 [8][12][1024][32]               off 37752832
// Yt   f16 [8][12][1024][32]               off 44044288
// Wf   f16 [72g16][12cb][64lane][8]        off 50335744  fragment-major qkv_w
// PWf  f16 [24g16][12cb][64lane][8]        off 51220480  fragment-major proj_w

__device__ inline float fexp2(float x) { return __builtin_exp2f(x); }

__device__ inline uint32_t pkrtz(float a, float b) {
  fp16x2 h = __builtin_amdgcn_cvt_pkrtz(a, b);
  union { fp16x2 h; uint32_t u; } cv; cv.h = h; return cv.u;
}

// ---------------- fused prep: pack Wf, pack PWf, transpose-convert x -> Xt -------
__launch_bounds__(256)
__global__ void k_prep(const float* __restrict__ qkv_w, const float* __restrict__ pw,
                       const float* __restrict__ x, _Float16* __restrict__ Wf,
                       _Float16* __restrict__ PWf, _Float16* __restrict__ Xt) {
  const int bid = blockIdx.x;
  if (bid < 288) {
    const float* src = (bid < 216) ? qkv_w : pw;
    _Float16* dst = (bid < 216) ? Wf : PWf;
    int cid = (bid < 216 ? bid : bid - 216) * 256 + threadIdx.x;
    int nchunks = (bid < 216) ? 55296 : 18432;
    if (cid >= nchunks) return;
    int lane = cid & 63;
    int t = cid >> 6;
    int cb = t % 12;
    int g16 = t / 12;
    const float* s = src + (long)(g16 * 16 + (lane & 15)) * 384 + cb * 32 + (lane >> 4) * 8;
    floatx4 a = *(const floatx4*)s;
    floatx4 b = *(const floatx4*)(s + 4);
    half8 h;
    #pragma unroll
    for (int j = 0; j < 4; j++) { h[j] = (_Float16)a[j]; h[j+4] = (_Float16)b[j]; }
    *(half8*)(dst + (long)cid * 8) = h;
  } else {
    int idx = bid - 288;
    const int cblk = idx % 12, nseg = (idx / 12) & 3, b = idx / 48;
    const float* S = x + ((long)b * 384 + cblk * 32) * 1024 + nseg * 256;
    _Float16* D = Xt + (long)b * 393216 + cblk * 32768 + (long)nseg * 256 * 32;
    __shared__ _Float16 T[32][264];
    const int wv = threadIdx.x >> 6, lane = threadIdx.x & 63;
    #pragma unroll
    for (int rr = 0; rr < 8; rr++) {
      int r = wv * 8 + rr;
      floatx4 v = *(const floatx4*)(S + (long)r * 1024 + lane * 4);
      half4 h;
      #pragma unroll
      for (int j = 0; j < 4; j++) h[j] = (_Float16)v[j];
      *(half4*)&T[r][lane * 4] = h;
    }
    __syncthreads();
    const int nn = threadIdx.x >> 3, c = (threadIdx.x & 7) * 4;
    #pragma unroll
    for (int p = 0; p < 8; p++) {
      int n = p * 32 + nn;
      half4 h;
      #pragma unroll
      for (int i = 0; i < 4; i++) h[i] = T[c + i][n];
      *(half4*)(D + (long)n * 32 + c) = h;
    }
  }
}

// ---------------- transpose f16: Yf [384][1024] -> Yt [12][1024][32] per b --------
__launch_bounds__(256)
__global__ void k_trh(const _Float16* __restrict__ src, _Float16* __restrict__ dst) {
  const int cblk = blockIdx.x, nseg = blockIdx.y, b = blockIdx.z;
  const _Float16* S = src + ((long)b * 384 + cblk * 32) * 1024 + nseg * 256;
  _Float16* D = dst + (long)b * 393216 + cblk * 32768 + (long)nseg * 256 * 32;
  __shared__ _Float16 T[32][264];
  const int wv = threadIdx.x >> 6, lane = threadIdx.x & 63;
  #pragma unroll
  for (int rr = 0; rr < 8; rr++) {
    int r = wv * 8 + rr;
    *(half4*)&T[r][lane * 4] = *(const half4*)(S + (long)r * 1024 + lane * 4);
  }
  __syncthreads();
  const int nn = threadIdx.x >> 3, c = (threadIdx.x & 7) * 4;
  #pragma unroll
  for (int p = 0; p < 8; p++) {
    int n = p * 32 + nn;
    half4 h;
    #pragma unroll
    for (int i = 0; i < 4; i++) h[i] = T[c + i][n];
    *(half4*)(D + (long)n * 32 + c) = h;
  }
}

// ---------------- QKV GEMM: Wf @ Xt per batch -> swizzled Q/K/V + GN partials -----
// A-fragments are identical across the 4 waves -> staged once into LDS (36KB),
// cutting Wf L2 traffic 4x. T (epilogue transpose buffer) aliases WA.
__launch_bounds__(256, 4)
__global__ void k_qkv(const _Float16* __restrict__ Xt, const _Float16* __restrict__ Wf,
                      _Float16* __restrict__ Qs, _Float16* __restrict__ Ks,
                      _Float16* __restrict__ Vs, float* __restrict__ gnpart) {
  const int tid = threadIdx.x;
  const int lane = tid & 63;
  const int wv = tid >> 6;
  const int l15 = lane & 15;
  const int g = lane >> 4;
  const int o0 = blockIdx.x * 48;
  const int n0 = blockIdx.y * 64;
  const int b = blockIdx.z;

  __shared__ __align__(16) _Float16 WA[18432];   // 36KB: A frags; aliased as T later
  __shared__ float red[8];

  // cooperative A-stage: wave wv stages frags wv*9 .. wv*9+8
  {
    const _Float16* wsrc = Wf + ((long)blockIdx.x * 36 + wv * 9) * 512 + lane * 8;
    uint4 wtmp[9];
    #pragma unroll
    for (int k = 0; k < 9; k++) wtmp[k] = *(const uint4*)(wsrc + k * 512);
    #pragma unroll
    for (int k = 0; k < 9; k++) *(uint4*)(&WA[(wv * 9 + k) * 512 + lane * 8]) = wtmp[k];
  }

  const int ncol = n0 + wv * 16 + l15;
  const _Float16* xp = Xt + (long)b * 393216 + (long)ncol * 32 + g * 8;
  half8 xb[12];
  #pragma unroll
  for (int cb = 0; cb < 12; cb++) xb[cb] = *(const half8*)(xp + cb * 32768);

  __syncthreads();

  floatx4 zero4 = {0.f, 0.f, 0.f, 0.f};
  floatx4 acc0 = zero4, acc1 = zero4, acc2 = zero4;

  #pragma unroll
  for (int cb = 0; cb < 12; cb++) {
    half8 a0 = *(const half8*)&WA[(cb) * 512 + lane * 8];
    half8 a1 = *(const half8*)&WA[(12 + cb) * 512 + lane * 8];
    half8 a2 = *(const half8*)&WA[(24 + cb) * 512 + lane * 8];
    acc0 = __builtin_amdgcn_mfma_f32_16x16x32_f16(a0, xb[cb], acc0, 0, 0, 0);
    acc1 = __builtin_amdgcn_mfma_f32_16x16x32_f16(a1, xb[cb], acc1, 0, 0, 0);
    acc2 = __builtin_amdgcn_mfma_f32_16x16x32_f16(a2, xb[cb], acc2, 0, 0, 0);
  }

  floatx4 acc[3] = {acc0, acc1, acc2};
  __syncthreads();                // all waves done reading WA; reuse as T
  _Float16* T = WA;               // max(64*52, 48*72) = 3456 halves

  if (o0 < 768) {
    #pragma unroll
    for (int rt = 0; rt < 3; rt++)
      #pragma unroll
      for (int r = 0; r < 4; r++)
        T[(wv * 16 + l15) * 52 + rt * 16 + g * 4 + r] = (_Float16)acc[rt][r];
    __syncthreads();
    const int qk = o0 >= 384;
    const int hh = (o0 - qk * 384) / 48;
    _Float16* base = (qk ? Ks : Qs) + (long)(b * 8 + hh) * 65536;
    #pragma unroll
    for (int it = 0; it < 2; it++) {
      int slot = it * 256 + tid;
      int ntl = slot >> 8;
      int t   = (slot >> 6) & 3;
      int ln  = slot & 63;
      int hi_s = ln >> 5, l31_s = ln & 31;
      int n_ = ntl * 32 + l31_s;
      int c0 = t * 16 + hi_s * 8;
      half8 val;
      #pragma unroll
      for (int j = 0; j < 8; j++) {
        int col = c0 + j;
        int d48 = col < 24 ? col : col - 8;
        bool isq = (col < 24) || (col >= 32 && col < 56);
        val[j] = isq ? T[n_ * 52 + d48] : (_Float16)0;
      }
      *(half8*)(base + ((((n0 >> 5) + ntl) * 4 + t) * 64 + ln) * 8) = val;
    }
    if (!qk) {
      // GN partial over q2 (d48 24..47) of this (head, 64-n) tile
      float s1 = 0.f, s2 = 0.f;
      int n_ = tid >> 2, k0 = (tid & 3) * 6;
      #pragma unroll
      for (int k = 0; k < 6; k++) {
        float v = (float)T[n_ * 52 + 24 + k0 + k];
        s1 += v; s2 += v * v;
      }
      #pragma unroll
      for (int off = 32; off > 0; off >>= 1) {
        s1 += __shfl_down(s1, off);
        s2 += __shfl_down(s2, off);
      }
      if ((tid & 63) == 0) { red[tid >> 6] = s1; red[4 + (tid >> 6)] = s2; }
      __syncthreads();
      if (tid == 0) {
        int slot = (b * 8 + hh) * 16 + (n0 >> 6);
        gnpart[slot * 2]     = red[0] + red[1] + red[2] + red[3];
        gnpart[slot * 2 + 1] = red[4] + red[5] + red[6] + red[7];
      }
    }
  } else {
    #pragma unroll
    for (int rt = 0; rt < 3; rt++)
      #pragma unroll
      for (int r = 0; r < 4; r++)
        T[(rt * 16 + g * 4 + r) * 72 + wv * 16 + l15] = (_Float16)acc[rt][r];
    __syncthreads();
    const int hh = (o0 - 768) / 48;
    _Float16* base = Vs + (long)(b * 8 + hh) * 65536;
    #pragma unroll
    for (int it = 0; it < 2; it++) {
      int slot = it * 256 + tid;
      int lwin = slot >> 8;
      int ckc  = (slot >> 6) & 3;
      int kc   = ckc & 1, c = ckc >> 1;
      int ln = slot & 63;
      int hi_s = ln >> 5, l31_s = ln & 31;
      int d48 = c * 32 + l31_s;
      half8 val;
      if (d48 < 48) {
        int mb = lwin * 32 + kc * 16 + hi_s * 4;
        half4 a = *(const half4*)&T[d48 * 72 + mb];
        half4 bq = *(const half4*)&T[d48 * 72 + mb + 8];
        val[0] = a[0]; val[1] = a[1]; val[2] = a[2]; val[3] = a[3];
        val[4] = bq[0]; val[5] = bq[1]; val[6] = bq[2]; val[7] = bq[3];
      } else {
        _Float16 f = (d48 == 48) ? (_Float16)1 : (_Float16)0;
        #pragma unroll
        for (int j = 0; j < 8; j++) val[j] = f;
      }
      *(half8*)(base + ((((n0 >> 5) + lwin) * 4 + ckc) * 64 + ln) * 8) = val;
    }
  }
}

// ---------------- fused dual-softmax attention: 8-wave coop, 64-key iterations ----
// (round-14 version, verified 51.2us) Wave = (ntile, branch). GN fold at Q-load;
// GN stats reduced lane-parallel from k_qkv's partials. K/V double-buffered in
// LDS (2x16KB), one barrier per 64-key pair. Epilogue: flat f16 Yf write
// (verified map); Yf -> Yt via k_trh.
__launch_bounds__(512, 4)
__global__ void k_attn(const _Float16* __restrict__ Qs, const _Float16* __restrict__ Ks,
                       const _Float16* __restrict__ Vs, const float* __restrict__ gnpart,
                       const float* __restrict__ lam, const float* __restrict__ gw,
                       const float* __restrict__ gb, _Float16* __restrict__ Yf) {
  const int tid = threadIdx.x;
  const int lane = tid & 63;
  const int wv = tid >> 6;          // 0..7
  const int l31 = lane & 31;
  const int hi = lane >> 5;
  const int id = blockIdx.x;
  const int bh = ((id >> 6) << 3) | (id & 7);
  const int ntlgrp = (id >> 3) & 7;
  const int br = wv & 1;
  const int ntile = ntlgrp * 4 + (wv >> 1);
  const int n0 = ntile * 32;
  const int b = bh >> 3, h = bh & 7;

  // Q load + folded GN / scale
  const _Float16* Qp = Qs + (long)bh * 65536 + (ntile * 256 + lane) * 8;
  half8 qra = *(const half8*)(Qp + (2 * br) * 512);
  half8 qrb = *(const half8*)(Qp + (2 * br + 1) * 512);
  half8 qfa, qfb;
  if (br == 0) {
    const float s1s = SCALE * LOG2E;
    #pragma unroll
    for (int j = 0; j < 8; j++) {
      qfa[j] = (_Float16)((float)qra[j] * s1s);
      qfb[j] = (_Float16)((float)qrb[j] * s1s);
    }
  } else {
    const int grp = h >> 2;
    const float* pp = gnpart + (b * 128 + grp * 64) * 2;
    float S1 = pp[lane * 2], S2 = pp[lane * 2 + 1];
    #pragma unroll
    for (int off = 1; off < 64; off <<= 1) {
      S1 += __shfl_xor(S1, off);
      S2 += __shfl_xor(S2, off);
    }
    float mean = S1 * (1.f / 98304.f);
    float rstd = rsqrtf(S2 * (1.f / 98304.f) - mean * mean + 1e-5f);
    float sl = SCALE * LOG2E * lam[h];
    const float* gwp = gw + h * 24;
    const float* gbp = gb + h * 24;
    #pragma unroll
    for (int j = 0; j < 8; j++) {
      qfa[j] = (_Float16)((((float)qra[j] - mean) * rstd * gwp[hi * 8 + j] + gbp[hi * 8 + j]) * sl);
      qfb[j] = (_Float16)((((float)qrb[j] - mean) * rstd * gwp[16 + j] + gbp[16 + j]) * sl);
    }
  }

  const _Float16* gK = Ks + (long)bh * 65536 + ((wv >> 2) * 2048 + (wv & 3) * 512) + lane * 8;
  const _Float16* gV = Vs + (long)bh * 65536 + ((wv >> 2) * 2048 + (wv & 3) * 512) + lane * 8;

  __shared__ __align__(16) char smem[32768];   // [2 bufs][K 8KB | V 8KB]; reused for reduction
  const int ldsK = wv * 1024 + lane * 16;
  const int ldsV = 8192 + wv * 1024 + lane * 16;

  floatx16 z16;
  #pragma unroll
  for (int i = 0; i < 16; i++) z16[i] = 0.f;
  floatx16 accA = z16, accB = z16;

  {
    uint4 a = *(const uint4*)gK;
    uint4 c = *(const uint4*)gV;
    *(uint4*)(smem + ldsK) = a;
    *(uint4*)(smem + ldsV) = c;
  }
  __syncthreads();

  #pragma unroll 2
  for (int i = 0; i < 16; i++) {
    const int cur = (i & 1) << 14;
    uint4 sa, sc;
    if (i < 15) {
      sa = *(const uint4*)(gK + (i + 1) * 4096);
      sc = *(const uint4*)(gV + (i + 1) * 4096);
    }
    #pragma unroll
    for (int j = 0; j < 2; j++) {
      const char* Kb = smem + cur + j * 4096;
      const char* Vb = smem + cur + 8192 + j * 4096;
      half8 kfa = *(const half8*)(Kb + (2 * br) * 1024 + lane * 16);
      half8 kfb = *(const half8*)(Kb + (2 * br + 1) * 1024 + lane * 16);

      floatx16 s = __builtin_amdgcn_mfma_f32_32x32x16_f16(kfa, qfa, z16, 0, 0, 0);
      s = __builtin_amdgcn_mfma_f32_32x32x16_f16(kfb, qfb, s, 0, 0, 0);

      half8 vf0 = *(const half8*)(Vb + lane * 16);
      half8 vf1 = *(const half8*)(Vb + 1024 + lane * 16);
      half8 vf2 = *(const half8*)(Vb + 2048 + lane * 16);
      half8 vf3 = *(const half8*)(Vb + 3072 + lane * 16);

      uint32_t u[8];
      #pragma unroll
      for (int q = 0; q < 8; q++)
        u[q] = pkrtz(fexp2(s[2 * q]), fexp2(s[2 * q + 1]));

      union { uint32_t u[4]; half8 h; } pa;
      pa.u[0] = u[0]; pa.u[1] = u[1]; pa.u[2] = u[2]; pa.u[3] = u[3];
      half8 pc0 = pa.h;
      pa.u[0] = u[4]; pa.u[1] = u[5]; pa.u[2] = u[6]; pa.u[3] = u[7];
      half8 pc1 = pa.h;

      accA = __builtin_amdgcn_mfma_f32_32x32x16_f16(pc0, vf0, accA, 0, 0, 0);
      accA = __builtin_amdgcn_mfma_f32_32x32x16_f16(pc1, vf1, accA, 0, 0, 0);
      accB = __builtin_amdgcn_mfma_f32_32x32x16_f16(pc0, vf2, accB, 0, 0, 0);
      accB = __builtin_amdgcn_mfma_f32_32x32x16_f16(pc1, vf3, accB, 0, 0, 0);
    }
    if (i < 15) {
      *(uint4*)(smem + (cur ^ 16384) + ldsK) = sa;
      *(uint4*)(smem + (cur ^ 16384) + ldsV) = sc;
    }
    __syncthreads();
  }

  // branch combine: odd waves dump accs, even waves combine + write Yf (flat f16)
  const int pairid = wv >> 1;
  float* rbuf = (float*)(smem + pairid * 8192);
  if (br == 1) {
    #pragma unroll
    for (int r = 0; r < 16; r++) {
      rbuf[r * 64 + lane] = accA[r];
      rbuf[(16 + r) * 64 + lane] = accB[r];
    }
  }
  __syncthreads();
  if (br == 0) {
    float a2a[16], a2b[16];
    #pragma unroll
    for (int r = 0; r < 16; r++) {
      a2a[r] = rbuf[r * 64 + lane];
      a2b[r] = rbuf[(16 + r) * 64 + lane];
    }
    _Float16* Ybh = Yf + (long)bh * 49152;
    const int src = (lane & 32) + 16;
    #pragma unroll
    for (int r = 0; r < 16; r++) {
      float i1 = __builtin_amdgcn_rcpf(__shfl(accB[r], src));
      float i2 = __builtin_amdgcn_rcpf(__shfl(a2b[r], src));
      int n = n0 + (r & 3) + 8 * ((r >> 2) & 3) + 4 * hi;
      float o0 = accA[r] * i1 - a2a[r] * i2;   // d = l31
      float o1 = accB[r] * i1 - a2b[r] * i2;   // d = 32 + l31 (valid < 48)
      int p0 = l31 >= 24;
      Ybh[p0 * 24576 + n * 24 + (l31 - p0 * 24)] = (_Float16)o0;
      if (l31 < 16) Ybh[24576 + n * 24 + 8 + l31] = (_Float16)o1;
    }
  }
}

// ---------------- proj GEMM: PWf @ Yt + b (A staged in LDS) ----------------
__launch_bounds__(256, 4)
__global__ void k_proj(const _Float16* __restrict__ Yt, const _Float16* __restrict__ PWf,
                       const float* __restrict__ PB, float* __restrict__ out) {
  const int tid = threadIdx.x, lane = tid & 63, wv = tid >> 6, l15 = lane & 15, g = lane >> 4;
  const int o0 = blockIdx.x * 64, m0 = blockIdx.y * 64, b = blockIdx.z;

  __shared__ __align__(16) _Float16 PA[24576];   // 48KB: 48 A frags

  {
    const _Float16* psrc = PWf + ((long)blockIdx.x * 48 + wv * 12) * 512 + lane * 8;
    uint4 ptmp[12];
    #pragma unroll
    for (int k = 0; k < 12; k++) ptmp[k] = *(const uint4*)(psrc + k * 512);
    #pragma unroll
    for (int k = 0; k < 12; k++) *(uint4*)(&PA[(wv * 12 + k) * 512 + lane * 8]) = ptmp[k];
  }

  const int mcol = m0 + wv * 16 + l15;
  const _Float16* yp = Yt + (long)b * 393216 + (long)mcol * 32 + g * 8;
  half8 yb[12];
  #pragma unroll
  for (int cb = 0; cb < 12; cb++) yb[cb] = *(const half8*)(yp + cb * 32768);

  __syncthreads();

  floatx4 zero4 = {0.f, 0.f, 0.f, 0.f};
  floatx4 acc0 = zero4, acc1 = zero4, acc2 = zero4, acc3 = zero4;

  #pragma unroll
  for (int cb = 0; cb < 12; cb++) {
    half8 a0 = *(const half8*)&PA[(cb) * 512 + lane * 8];
    half8 a1 = *(const half8*)&PA[(12 + cb) * 512 + lane * 8];
    half8 a2 = *(const half8*)&PA[(24 + cb) * 512 + lane * 8];
    half8 a3 = *(const half8*)&PA[(36 + cb) * 512 + lane * 8];
    acc0 = __builtin_amdgcn_mfma_f32_16x16x32_f16(a0, yb[cb], acc0, 0, 0, 0);
    acc1 = __builtin_amdgcn_mfma_f32_16x16x32_f16(a1, yb[cb], acc1, 0, 0, 0);
    acc2 = __builtin_amdgcn_mfma_f32_16x16x32_f16(a2, yb[cb], acc2, 0, 0, 0);
    acc3 = __builtin_amdgcn_mfma_f32_16x16x32_f16(a3, yb[cb], acc3, 0, 0, 0);
  }

  floatx4 acc[4] = {acc0, acc1, acc2, acc3};
  #pragma unroll
  for (int rt = 0; rt < 4; rt++) {
    int o_ = o0 + rt * 16 + g * 4;
    #pragma unroll
    for (int r = 0; r < 4; r++) {
      out[(long)(b * 384 + o_ + r) * 1024 + mcol] = acc[rt][r] + PB[o_ + r];
    }
  }
}

extern "C" void kernel_launch(void* const* d_in, const int* in_sizes, int n_in,
                              void* d_out, int out_size, void* d_ws, size_t ws_size,
                              hipStream_t stream) {
  const float* x     = (const float*)d_in[0];
  const float* qkv_w = (const float*)d_in[1];
  const float* lam   = (const float*)d_in[2];
  const float* gw    = (const float*)d_in[3];
  const float* gb    = (const float*)d_in[4];
  const float* pw    = (const float*)d_in[5];
  const float* pb    = (const float*)d_in[6];
  float* out = (float*)d_out;
  char* ws = (char*)d_ws;
  _Float16* Qs  = (_Float16*)ws;
  _Float16* Ks  = (_Float16*)(ws + 8388608);
  _Float16* Vs  = (_Float16*)(ws + 16777216);
  float* gnpart   = (float*)(ws + 25165824);
  _Float16* Yf  = (_Float16*)(ws + 26214400);
  _Float16* Xt  = (_Float16*)(ws + 37752832);
  _Float16* Yt  = (_Float16*)(ws + 44044288);
  _Float16* Wf  = (_Float16*)(ws + 50335744);
  _Float16* PWf = (_Float16*)(ws + 51220480);

  hipLaunchKernelGGL(k_prep,    dim3(672),        dim3(256), 0, stream, qkv_w, pw, x, Wf, PWf, Xt);
  hipLaunchKernelGGL(k_qkv,     dim3(24, 16, 8),  dim3(256), 0, stream, Xt, Wf, Qs, Ks, Vs, gnpart);
  hipLaunchKernelGGL(k_attn,    dim3(512),        dim3(512), 0, stream, Qs, Ks, Vs, gnpart, lam, gw, gb, Yf);
  hipLaunchKernelGGL(k_trh,     dim3(12, 4, 8),   dim3(256), 0, stream, Yf, Yt);
  hipLaunchKernelGGL(k_proj,    dim3(6, 16, 8),   dim3(256), 0, stream, Yt, PWf, pb, out);
}

// Round 17
// 84.109 us; speedup vs baseline: 1.0148x; 1.0148x over previous
//
#include <hip/hip_runtime.h>
#include <hip/hip_bf16.h>
#include <stdint.h>

typedef _Float16 half8 __attribute__((ext_vector_type(8)));
typedef _Float16 half4 __attribute__((ext_vector_type(4)));
typedef __fp16 fp16x2 __attribute__((ext_vector_type(2)));
typedef float floatx4 __attribute__((ext_vector_type(4)));
typedef float floatx16 __attribute__((ext_vector_type(16)));

#define SCALE 0.14433756729740643f
#define LOG2E 1.4426950408889634f

// ws layout (bytes):
// Qswz f16 [64bh][32ntile][4t][64lane][8]  off 0         fragment-major Q (raw; GN folded in attn)
// Kswz f16 [64bh][32win][4t][64lane][8]    off 8388608   fragment-major K
// Vswz f16 [64bh][32win][2c][2kc][64][8]   off 16777216  fragment-major V
// gnpart f32 [8b][8h][16nblk][2]           off 25165824  per-(head,nblk) GN partials
// Yf   f16 [8][384][1024]                  off 26214400  scrambled pre-proj (flat order, f16)
// Xt   f16 [8][12][1024][32]               off 37752832
// Yt   f16 [8][12][1024][32]               off 44044288
// Wf   f16 [72g16][12cb][64lane][8]        off 50335744  fragment-major qkv_w
// PWf  f16 [24g16][12cb][64lane][8]        off 51220480  fragment-major proj_w

__device__ inline float fexp2(float x) { return __builtin_exp2f(x); }

__device__ inline uint32_t pkrtz(float a, float b) {
  fp16x2 h = __builtin_amdgcn_cvt_pkrtz(a, b);
  union { fp16x2 h; uint32_t u; } cv; cv.h = h; return cv.u;
}

// ---------------- fused prep: pack Wf, pack PWf, transpose-convert x -> Xt -------
__launch_bounds__(256)
__global__ void k_prep(const float* __restrict__ qkv_w, const float* __restrict__ pw,
                       const float* __restrict__ x, _Float16* __restrict__ Wf,
                       _Float16* __restrict__ PWf, _Float16* __restrict__ Xt) {
  const int bid = blockIdx.x;
  if (bid < 288) {
    const float* src = (bid < 216) ? qkv_w : pw;
    _Float16* dst = (bid < 216) ? Wf : PWf;
    int cid = (bid < 216 ? bid : bid - 216) * 256 + threadIdx.x;
    int nchunks = (bid < 216) ? 55296 : 18432;
    if (cid >= nchunks) return;
    int lane = cid & 63;
    int t = cid >> 6;
    int cb = t % 12;
    int g16 = t / 12;
    const float* s = src + (long)(g16 * 16 + (lane & 15)) * 384 + cb * 32 + (lane >> 4) * 8;
    floatx4 a = *(const floatx4*)s;
    floatx4 b = *(const floatx4*)(s + 4);
    half8 h;
    #pragma unroll
    for (int j = 0; j < 4; j++) { h[j] = (_Float16)a[j]; h[j+4] = (_Float16)b[j]; }
    *(half8*)(dst + (long)cid * 8) = h;
  } else {
    int idx = bid - 288;
    const int cblk = idx % 12, nseg = (idx / 12) & 3, b = idx / 48;
    const float* S = x + ((long)b * 384 + cblk * 32) * 1024 + nseg * 256;
    _Float16* D = Xt + (long)b * 393216 + cblk * 32768 + (long)nseg * 256 * 32;
    __shared__ _Float16 T[32][264];
    const int wv = threadIdx.x >> 6, lane = threadIdx.x & 63;
    #pragma unroll
    for (int rr = 0; rr < 8; rr++) {
      int r = wv * 8 + rr;
      floatx4 v = *(const floatx4*)(S + (long)r * 1024 + lane * 4);
      half4 h;
      #pragma unroll
      for (int j = 0; j < 4; j++) h[j] = (_Float16)v[j];
      *(half4*)&T[r][lane * 4] = h;
    }
    __syncthreads();
    const int nn = threadIdx.x >> 3, c = (threadIdx.x & 7) * 4;
    #pragma unroll
    for (int p = 0; p < 8; p++) {
      int n = p * 32 + nn;
      half4 h;
      #pragma unroll
      for (int i = 0; i < 4; i++) h[i] = T[c + i][n];
      *(half4*)(D + (long)n * 32 + c) = h;
    }
  }
}

// ---------------- transpose f16: Yf [384][1024] -> Yt [12][1024][32] per b --------
__launch_bounds__(256)
__global__ void k_trh(const _Float16* __restrict__ src, _Float16* __restrict__ dst) {
  const int cblk = blockIdx.x, nseg = blockIdx.y, b = blockIdx.z;
  const _Float16* S = src + ((long)b * 384 + cblk * 32) * 1024 + nseg * 256;
  _Float16* D = dst + (long)b * 393216 + cblk * 32768 + (long)nseg * 256 * 32;
  __shared__ _Float16 T[32][264];
  const int wv = threadIdx.x >> 6, lane = threadIdx.x & 63;
  #pragma unroll
  for (int rr = 0; rr < 8; rr++) {
    int r = wv * 8 + rr;
    *(half4*)&T[r][lane * 4] = *(const half4*)(S + (long)r * 1024 + lane * 4);
  }
  __syncthreads();
  const int nn = threadIdx.x >> 3, c = (threadIdx.x & 7) * 4;
  #pragma unroll
  for (int p = 0; p < 8; p++) {
    int n = p * 32 + nn;
    half4 h;
    #pragma unroll
    for (int i = 0; i < 4; i++) h[i] = T[c + i][n];
    *(half4*)(D + (long)n * 32 + c) = h;
  }
}

// ---------------- QKV GEMM: Wf @ Xt per batch -> swizzled Q/K/V + GN partials -----
__launch_bounds__(256, 4)
__global__ void k_qkv(const _Float16* __restrict__ Xt, const _Float16* __restrict__ Wf,
                      _Float16* __restrict__ Qs, _Float16* __restrict__ Ks,
                      _Float16* __restrict__ Vs, float* __restrict__ gnpart) {
  const int tid = threadIdx.x;
  const int lane = tid & 63;
  const int wv = tid >> 6;
  const int l15 = lane & 15;
  const int g = lane >> 4;
  const int o0 = blockIdx.x * 48;
  const int n0 = blockIdx.y * 64;
  const int b = blockIdx.z;

  __shared__ __align__(16) _Float16 WA[18432];   // 36KB: A frags; aliased as T later
  __shared__ float red[8];

  {
    const _Float16* wsrc = Wf + ((long)blockIdx.x * 36 + wv * 9) * 512 + lane * 8;
    uint4 wtmp[9];
    #pragma unroll
    for (int k = 0; k < 9; k++) wtmp[k] = *(const uint4*)(wsrc + k * 512);
    #pragma unroll
    for (int k = 0; k < 9; k++) *(uint4*)(&WA[(wv * 9 + k) * 512 + lane * 8]) = wtmp[k];
  }

  const int ncol = n0 + wv * 16 + l15;
  const _Float16* xp = Xt + (long)b * 393216 + (long)ncol * 32 + g * 8;
  half8 xb[12];
  #pragma unroll
  for (int cb = 0; cb < 12; cb++) xb[cb] = *(const half8*)(xp + cb * 32768);

  __syncthreads();

  floatx4 zero4 = {0.f, 0.f, 0.f, 0.f};
  floatx4 acc0 = zero4, acc1 = zero4, acc2 = zero4;

  #pragma unroll
  for (int cb = 0; cb < 12; cb++) {
    half8 a0 = *(const half8*)&WA[(cb) * 512 + lane * 8];
    half8 a1 = *(const half8*)&WA[(12 + cb) * 512 + lane * 8];
    half8 a2 = *(const half8*)&WA[(24 + cb) * 512 + lane * 8];
    acc0 = __builtin_amdgcn_mfma_f32_16x16x32_f16(a0, xb[cb], acc0, 0, 0, 0);
    acc1 = __builtin_amdgcn_mfma_f32_16x16x32_f16(a1, xb[cb], acc1, 0, 0, 0);
    acc2 = __builtin_amdgcn_mfma_f32_16x16x32_f16(a2, xb[cb], acc2, 0, 0, 0);
  }

  floatx4 acc[3] = {acc0, acc1, acc2};
  __syncthreads();
  _Float16* T = WA;

  if (o0 < 768) {
    #pragma unroll
    for (int rt = 0; rt < 3; rt++)
      #pragma unroll
      for (int r = 0; r < 4; r++)
        T[(wv * 16 + l15) * 52 + rt * 16 + g * 4 + r] = (_Float16)acc[rt][r];
    __syncthreads();
    const int qk = o0 >= 384;
    const int hh = (o0 - qk * 384) / 48;
    _Float16* base = (qk ? Ks : Qs) + (long)(b * 8 + hh) * 65536;
    #pragma unroll
    for (int it = 0; it < 2; it++) {
      int slot = it * 256 + tid;
      int ntl = slot >> 8;
      int t   = (slot >> 6) & 3;
      int ln  = slot & 63;
      int hi_s = ln >> 5, l31_s = ln & 31;
      int n_ = ntl * 32 + l31_s;
      int c0 = t * 16 + hi_s * 8;
      half8 val;
      #pragma unroll
      for (int j = 0; j < 8; j++) {
        int col = c0 + j;
        int d48 = col < 24 ? col : col - 8;
        bool isq = (col < 24) || (col >= 32 && col < 56);
        val[j] = isq ? T[n_ * 52 + d48] : (_Float16)0;
      }
      *(half8*)(base + ((((n0 >> 5) + ntl) * 4 + t) * 64 + ln) * 8) = val;
    }
    if (!qk) {
      float s1 = 0.f, s2 = 0.f;
      int n_ = tid >> 2, k0 = (tid & 3) * 6;
      #pragma unroll
      for (int k = 0; k < 6; k++) {
        float v = (float)T[n_ * 52 + 24 + k0 + k];
        s1 += v; s2 += v * v;
      }
      #pragma unroll
      for (int off = 32; off > 0; off >>= 1) {
        s1 += __shfl_down(s1, off);
        s2 += __shfl_down(s2, off);
      }
      if ((tid & 63) == 0) { red[tid >> 6] = s1; red[4 + (tid >> 6)] = s2; }
      __syncthreads();
      if (tid == 0) {
        int slot = (b * 8 + hh) * 16 + (n0 >> 6);
        gnpart[slot * 2]     = red[0] + red[1] + red[2] + red[3];
        gnpart[slot * 2 + 1] = red[4] + red[5] + red[6] + red[7];
      }
    }
  } else {
    #pragma unroll
    for (int rt = 0; rt < 3; rt++)
      #pragma unroll
      for (int r = 0; r < 4; r++)
        T[(rt * 16 + g * 4 + r) * 72 + wv * 16 + l15] = (_Float16)acc[rt][r];
    __syncthreads();
    const int hh = (o0 - 768) / 48;
    _Float16* base = Vs + (long)(b * 8 + hh) * 65536;
    #pragma unroll
    for (int it = 0; it < 2; it++) {
      int slot = it * 256 + tid;
      int lwin = slot >> 8;
      int ckc  = (slot >> 6) & 3;
      int kc   = ckc & 1, c = ckc >> 1;
      int ln = slot & 63;
      int hi_s = ln >> 5, l31_s = ln & 31;
      int d48 = c * 32 + l31_s;
      half8 val;
      if (d48 < 48) {
        int mb = lwin * 32 + kc * 16 + hi_s * 4;
        half4 a = *(const half4*)&T[d48 * 72 + mb];
        half4 bq = *(const half4*)&T[d48 * 72 + mb + 8];
        val[0] = a[0]; val[1] = a[1]; val[2] = a[2]; val[3] = a[3];
        val[4] = bq[0]; val[5] = bq[1]; val[6] = bq[2]; val[7] = bq[3];
      } else {
        _Float16 f = (d48 == 48) ? (_Float16)1 : (_Float16)0;
        #pragma unroll
        for (int j = 0; j < 8; j++) val[j] = f;
      }
      *(half8*)(base + ((((n0 >> 5) + lwin) * 4 + ckc) * 64 + ln) * 8) = val;
    }
  }
}

// ---------------- fused dual-softmax attention: both branches per wave -----------
// Block = 4 waves = 4 ntiles (one ntile-group); each wave computes BOTH branches
// (2-wide in-wave ILP: exp of branch1 overlaps branch2's MFMA chain). Same
// whole-head K/V LDS staging (2x16KB dbuf, each wave stages 2KB K + 2KB V per
// 64-key pair, one barrier per pair). V LDS-reads halve vs branch-split waves;
// the branch-combine phase disappears (diff computed in-register). Epilogue:
// flat f16 Yf write (verified map); Yf -> Yt via k_trh.
__launch_bounds__(256, 2)
__global__ void k_attn(const _Float16* __restrict__ Qs, const _Float16* __restrict__ Ks,
                       const _Float16* __restrict__ Vs, const float* __restrict__ gnpart,
                       const float* __restrict__ lam, const float* __restrict__ gw,
                       const float* __restrict__ gb, _Float16* __restrict__ Yf) {
  const int tid = threadIdx.x;
  const int lane = tid & 63;
  const int wv = tid >> 6;          // 0..3 = ntile within group
  const int l31 = lane & 31;
  const int hi = lane >> 5;
  const int id = blockIdx.x;
  const int bh = ((id >> 6) << 3) | (id & 7);
  const int ntlgrp = (id >> 3) & 7;
  const int ntile = ntlgrp * 4 + wv;
  const int n0 = ntile * 32;
  const int b = bh >> 3, h = bh & 7;

  // Q load + folded GN / scale (both branches)
  const _Float16* Qp = Qs + (long)bh * 65536 + (ntile * 256 + lane) * 8;
  half8 qr0a = *(const half8*)(Qp);
  half8 qr0b = *(const half8*)(Qp + 512);
  half8 qr1a = *(const half8*)(Qp + 1024);
  half8 qr1b = *(const half8*)(Qp + 1536);
  half8 qf0a, qf0b, qf1a, qf1b;
  {
    const float s1s = SCALE * LOG2E;
    #pragma unroll
    for (int j = 0; j < 8; j++) {
      qf0a[j] = (_Float16)((float)qr0a[j] * s1s);
      qf0b[j] = (_Float16)((float)qr0b[j] * s1s);
    }
    const int grp = h >> 2;
    const float* pp = gnpart + (b * 128 + grp * 64) * 2;
    float S1 = pp[lane * 2], S2 = pp[lane * 2 + 1];
    #pragma unroll
    for (int off = 1; off < 64; off <<= 1) {
      S1 += __shfl_xor(S1, off);
      S2 += __shfl_xor(S2, off);
    }
    float mean = S1 * (1.f / 98304.f);
    float rstd = rsqrtf(S2 * (1.f / 98304.f) - mean * mean + 1e-5f);
    float sl = s1s * lam[h];
    const float* gwp = gw + h * 24;
    const float* gbp = gb + h * 24;
    #pragma unroll
    for (int j = 0; j < 8; j++) {
      qf1a[j] = (_Float16)((((float)qr1a[j] - mean) * rstd * gwp[hi * 8 + j] + gbp[hi * 8 + j]) * sl);
      qf1b[j] = (_Float16)((((float)qr1b[j] - mean) * rstd * gwp[16 + j] + gbp[16 + j]) * sl);
    }
  }

  // staging: wave wv stages quarter wv of each 64-key pair (2KB K + 2KB V)
  const _Float16* gK = Ks + (long)bh * 65536 + wv * 1024 + lane * 8;
  const _Float16* gV = Vs + (long)bh * 65536 + wv * 1024 + lane * 8;

  __shared__ __align__(16) char smem[32768];   // [2 bufs][K 8KB | V 8KB]
  const int ldsK0 = wv * 2048 + lane * 16;
  const int ldsV0 = 8192 + wv * 2048 + lane * 16;

  floatx16 z16;
  #pragma unroll
  for (int i = 0; i < 16; i++) z16[i] = 0.f;
  floatx16 acc1A = z16, acc1B = z16, acc2A = z16, acc2B = z16;

  // prologue: stage pair 0 into buf0
  {
    uint4 k0 = *(const uint4*)gK;
    uint4 k1 = *(const uint4*)(gK + 512);
    uint4 v0 = *(const uint4*)gV;
    uint4 v1 = *(const uint4*)(gV + 512);
    *(uint4*)(smem + ldsK0) = k0;
    *(uint4*)(smem + ldsK0 + 1024) = k1;
    *(uint4*)(smem + ldsV0) = v0;
    *(uint4*)(smem + ldsV0 + 1024) = v1;
  }
  __syncthreads();

  #pragma unroll 2
  for (int i = 0; i < 16; i++) {
    const int cur = (i & 1) << 14;
    uint4 sk0, sk1, sv0, sv1;
    if (i < 15) {                                  // issue next-pair loads early
      sk0 = *(const uint4*)(gK + (i + 1) * 4096);
      sk1 = *(const uint4*)(gK + (i + 1) * 4096 + 512);
      sv0 = *(const uint4*)(gV + (i + 1) * 4096);
      sv1 = *(const uint4*)(gV + (i + 1) * 4096 + 512);
    }
    #pragma unroll
    for (int j = 0; j < 2; j++) {
      const char* Kb = smem + cur + j * 4096;
      const char* Vb = smem + cur + 8192 + j * 4096;
      half8 kf0a = *(const half8*)(Kb + lane * 16);
      half8 kf0b = *(const half8*)(Kb + 1024 + lane * 16);
      half8 kf1a = *(const half8*)(Kb + 2048 + lane * 16);
      half8 kf1b = *(const half8*)(Kb + 3072 + lane * 16);

      floatx16 s1 = __builtin_amdgcn_mfma_f32_32x32x16_f16(kf0a, qf0a, z16, 0, 0, 0);
      s1 = __builtin_amdgcn_mfma_f32_32x32x16_f16(kf0b, qf0b, s1, 0, 0, 0);
      floatx16 s2 = __builtin_amdgcn_mfma_f32_32x32x16_f16(kf1a, qf1a, z16, 0, 0, 0);
      s2 = __builtin_amdgcn_mfma_f32_32x32x16_f16(kf1b, qf1b, s2, 0, 0, 0);

      half8 vf0 = *(const half8*)(Vb + lane * 16);
      half8 vf1 = *(const half8*)(Vb + 1024 + lane * 16);
      half8 vf2 = *(const half8*)(Vb + 2048 + lane * 16);
      half8 vf3 = *(const half8*)(Vb + 3072 + lane * 16);

      uint32_t u1[8], u2[8];
      #pragma unroll
      for (int q = 0; q < 8; q++) {
        u1[q] = pkrtz(fexp2(s1[2 * q]), fexp2(s1[2 * q + 1]));
        u2[q] = pkrtz(fexp2(s2[2 * q]), fexp2(s2[2 * q + 1]));
      }

      union { uint32_t u[4]; half8 h; } pa;
      pa.u[0] = u1[0]; pa.u[1] = u1[1]; pa.u[2] = u1[2]; pa.u[3] = u1[3];
      half8 p1c0 = pa.h;
      pa.u[0] = u1[4]; pa.u[1] = u1[5]; pa.u[2] = u1[6]; pa.u[3] = u1[7];
      half8 p1c1 = pa.h;
      pa.u[0] = u2[0]; pa.u[1] = u2[1]; pa.u[2] = u2[2]; pa.u[3] = u2[3];
      half8 p2c0 = pa.h;
      pa.u[0] = u2[4]; pa.u[1] = u2[5]; pa.u[2] = u2[6]; pa.u[3] = u2[7];
      half8 p2c1 = pa.h;

      acc1A = __builtin_amdgcn_mfma_f32_32x32x16_f16(p1c0, vf0, acc1A, 0, 0, 0);
      acc1A = __builtin_amdgcn_mfma_f32_32x32x16_f16(p1c1, vf1, acc1A, 0, 0, 0);
      acc1B = __builtin_amdgcn_mfma_f32_32x32x16_f16(p1c0, vf2, acc1B, 0, 0, 0);
      acc1B = __builtin_amdgcn_mfma_f32_32x32x16_f16(p1c1, vf3, acc1B, 0, 0, 0);
      acc2A = __builtin_amdgcn_mfma_f32_32x32x16_f16(p2c0, vf0, acc2A, 0, 0, 0);
      acc2A = __builtin_amdgcn_mfma_f32_32x32x16_f16(p2c1, vf1, acc2A, 0, 0, 0);
      acc2B = __builtin_amdgcn_mfma_f32_32x32x16_f16(p2c0, vf2, acc2B, 0, 0, 0);
      acc2B = __builtin_amdgcn_mfma_f32_32x32x16_f16(p2c1, vf3, acc2B, 0, 0, 0);
    }
    if (i < 15) {                                  // write into the other buffer
      const int nxt = cur ^ 16384;
      *(uint4*)(smem + nxt + ldsK0) = sk0;
      *(uint4*)(smem + nxt + ldsK0 + 1024) = sk1;
      *(uint4*)(smem + nxt + ldsV0) = sv0;
      *(uint4*)(smem + nxt + ldsV0 + 1024) = sv1;
    }
    __syncthreads();
  }

  // epilogue: diff in-register; denominators at col 48 (l31==16 of B accs)
  {
    _Float16* Ybh = Yf + (long)bh * 49152;
    const int src = (lane & 32) + 16;
    #pragma unroll
    for (int r = 0; r < 16; r++) {
      float i1 = __builtin_amdgcn_rcpf(__shfl(acc1B[r], src));
      float i2 = __builtin_amdgcn_rcpf(__shfl(acc2B[r], src));
      int n = n0 + (r & 3) + 8 * ((r >> 2) & 3) + 4 * hi;
      float o0 = acc1A[r] * i1 - acc2A[r] * i2;   // d = l31
      float o1 = acc1B[r] * i1 - acc2B[r] * i2;   // d = 32 + l31 (valid < 48)
      int p0 = l31 >= 24;
      Ybh[p0 * 24576 + n * 24 + (l31 - p0 * 24)] = (_Float16)o0;
      if (l31 < 16) Ybh[24576 + n * 24 + 8 + l31] = (_Float16)o1;
    }
  }
}

// ---------------- proj GEMM: PWf @ Yt + b (A staged in LDS) ----------------
__launch_bounds__(256, 4)
__global__ void k_proj(const _Float16* __restrict__ Yt, const _Float16* __restrict__ PWf,
                       const float* __restrict__ PB, float* __restrict__ out) {
  const int tid = threadIdx.x, lane = tid & 63, wv = tid >> 6, l15 = lane & 15, g = lane >> 4;
  const int o0 = blockIdx.x * 64, m0 = blockIdx.y * 64, b = blockIdx.z;

  __shared__ __align__(16) _Float16 PA[24576];   // 48KB: 48 A frags

  {
    const _Float16* psrc = PWf + ((long)blockIdx.x * 48 + wv * 12) * 512 + lane * 8;
    uint4 ptmp[12];
    #pragma unroll
    for (int k = 0; k < 12; k++) ptmp[k] = *(const uint4*)(psrc + k * 512);
    #pragma unroll
    for (int k = 0; k < 12; k++) *(uint4*)(&PA[(wv * 12 + k) * 512 + lane * 8]) = ptmp[k];
  }

  const int mcol = m0 + wv * 16 + l15;
  const _Float16* yp = Yt + (long)b * 393216 + (long)mcol * 32 + g * 8;
  half8 yb[12];
  #pragma unroll
  for (int cb = 0; cb < 12; cb++) yb[cb] = *(const half8*)(yp + cb * 32768);

  __syncthreads();

  floatx4 zero4 = {0.f, 0.f, 0.f, 0.f};
  floatx4 acc0 = zero4, acc1 = zero4, acc2 = zero4, acc3 = zero4;

  #pragma unroll
  for (int cb = 0; cb < 12; cb++) {
    half8 a0 = *(const half8*)&PA[(cb) * 512 + lane * 8];
    half8 a1 = *(const half8*)&PA[(12 + cb) * 512 + lane * 8];
    half8 a2 = *(const half8*)&PA[(24 + cb) * 512 + lane * 8];
    half8 a3 = *(const half8*)&PA[(36 + cb) * 512 + lane * 8];
    acc0 = __builtin_amdgcn_mfma_f32_16x16x32_f16(a0, yb[cb], acc0, 0, 0, 0);
    acc1 = __builtin_amdgcn_mfma_f32_16x16x32_f16(a1, yb[cb], acc1, 0, 0, 0);
    acc2 = __builtin_amdgcn_mfma_f32_16x16x32_f16(a2, yb[cb], acc2, 0, 0, 0);
    acc3 = __builtin_amdgcn_mfma_f32_16x16x32_f16(a3, yb[cb], acc3, 0, 0, 0);
  }

  floatx4 acc[4] = {acc0, acc1, acc2, acc3};
  #pragma unroll
  for (int rt = 0; rt < 4; rt++) {
    int o_ = o0 + rt * 16 + g * 4;
    #pragma unroll
    for (int r = 0; r < 4; r++) {
      out[(long)(b * 384 + o_ + r) * 1024 + mcol] = acc[rt][r] + PB[o_ + r];
    }
  }
}

extern "C" void kernel_launch(void* const* d_in, const int* in_sizes, int n_in,
                              void* d_out, int out_size, void* d_ws, size_t ws_size,
                              hipStream_t stream) {
  const float* x     = (const float*)d_in[0];
  const float* qkv_w = (const float*)d_in[1];
  const float* lam   = (const float*)d_in[2];
  const float* gw    = (const float*)d_in[3];
  const float* gb    = (const float*)d_in[4];
  const float* pw    = (const float*)d_in[5];
  const float* pb    = (const float*)d_in[6];
  float* out = (float*)d_out;
  char* ws = (char*)d_ws;
  _Float16* Qs  = (_Float16*)ws;
  _Float16* Ks  = (_Float16*)(ws + 8388608);
  _Float16* Vs  = (_Float16*)(ws + 16777216);
  float* gnpart   = (float*)(ws + 25165824);
  _Float16* Yf  = (_Float16*)(ws + 26214400);
  _Float16* Xt  = (_Float16*)(ws + 37752832);
  _Float16* Yt  = (_Float16*)(ws + 44044288);
  _Float16* Wf  = (_Float16*)(ws + 50335744);
  _Float16* PWf = (_Float16*)(ws + 51220480);

  hipLaunchKernelGGL(k_prep,    dim3(672),        dim3(256), 0, stream, qkv_w, pw, x, Wf, PWf, Xt);
  hipLaunchKernelGGL(k_qkv,     dim3(24, 16, 8),  dim3(256), 0, stream, Xt, Wf, Qs, Ks, Vs, gnpart);
  hipLaunchKernelGGL(k_attn,    dim3(512),        dim3(256), 0, stream, Qs, Ks, Vs, gnpart, lam, gw, gb, Yf);
  hipLaunchKernelGGL(k_trh,     dim3(12, 4, 8),   dim3(256), 0, stream, Yf, Yt);
  hipLaunchKernelGGL(k_proj,    dim3(6, 16, 8),   dim3(256), 0, stream, Yt, PWf, pb, out);
}

// Round 19
// 83.787 us; speedup vs baseline: 1.0187x; 1.0038x over previous
//
#include <hip/hip_runtime.h>
#include <hip/hip_bf16.h>
#include <stdint.h>

typedef _Float16 half8 __attribute__((ext_vector_type(8)));
typedef _Float16 half4 __attribute__((ext_vector_type(4)));
typedef __fp16 fp16x2 __attribute__((ext_vector_type(2)));
typedef float floatx4 __attribute__((ext_vector_type(4)));
typedef float floatx16 __attribute__((ext_vector_type(16)));

#define SCALE 0.14433756729740643f
#define LOG2E 1.4426950408889634f

// ws layout (bytes):
// Qswz f16 [64bh][32ntile][4t][64lane][8]  off 0         fragment-major Q (raw; GN folded in attn)
// Kswz f16 [64bh][32win][4t][64lane][8]    off 8388608   fragment-major K
// Vswz f16 [64bh][32win][2c][2kc][64][8]   off 16777216  fragment-major V
// gnpart f32 [8b][8h][16nblk][2]           off 25165824  per-(head,nblk) GN partials
// Yf   f16 [8][384][1024]                  off 26214400  pre-proj, channel-major flat
// Xt   f16 [8][12][1024][32]               off 37752832
// Yt   f16 [8][12][1024][32]               off 44044288
// Wf   f16 [72g16][12cb][64lane][8]        off 50335744  fragment-major qkv_w
// PWf  f16 [24g16][12cb][64lane][8]        off 51220480  fragment-major proj_w (natural k-order)

__device__ inline float fexp2(float x) { return __builtin_exp2f(x); }

__device__ inline uint32_t pkrtz(float a, float b) {
  fp16x2 h = __builtin_amdgcn_cvt_pkrtz(a, b);
  union { fp16x2 h; uint32_t u; } cv; cv.h = h; return cv.u;
}

// ---------------- fused prep: pack Wf, pack PWf, transpose-convert x -> Xt -------
__launch_bounds__(256)
__global__ void k_prep(const float* __restrict__ qkv_w, const float* __restrict__ pw,
                       const float* __restrict__ x, _Float16* __restrict__ Wf,
                       _Float16* __restrict__ PWf, _Float16* __restrict__ Xt) {
  const int bid = blockIdx.x;
  if (bid < 288) {
    const float* src = (bid < 216) ? qkv_w : pw;
    _Float16* dst = (bid < 216) ? Wf : PWf;
    int cid = (bid < 216 ? bid : bid - 216) * 256 + threadIdx.x;
    int nchunks = (bid < 216) ? 55296 : 18432;
    if (cid >= nchunks) return;
    int lane = cid & 63;
    int t = cid >> 6;
    int cb = t % 12;
    int g16 = t / 12;
    const float* s = src + (long)(g16 * 16 + (lane & 15)) * 384 + cb * 32 + (lane >> 4) * 8;
    floatx4 a = *(const floatx4*)s;
    floatx4 b = *(const floatx4*)(s + 4);
    half8 h;
    #pragma unroll
    for (int j = 0; j < 4; j++) { h[j] = (_Float16)a[j]; h[j+4] = (_Float16)b[j]; }
    *(half8*)(dst + (long)cid * 8) = h;
  } else {
    int idx = bid - 288;
    const int cblk = idx % 12, nseg = (idx / 12) & 3, b = idx / 48;
    const float* S = x + ((long)b * 384 + cblk * 32) * 1024 + nseg * 256;
    _Float16* D = Xt + (long)b * 393216 + cblk * 32768 + (long)nseg * 256 * 32;
    __shared__ _Float16 T[32][264];
    const int wv = threadIdx.x >> 6, lane = threadIdx.x & 63;
    #pragma unroll
    for (int rr = 0; rr < 8; rr++) {
      int r = wv * 8 + rr;
      floatx4 v = *(const floatx4*)(S + (long)r * 1024 + lane * 4);
      half4 h;
      #pragma unroll
      for (int j = 0; j < 4; j++) h[j] = (_Float16)v[j];
      *(half4*)&T[r][lane * 4] = h;
    }
    __syncthreads();
    const int nn = threadIdx.x >> 3, c = (threadIdx.x & 7) * 4;
    #pragma unroll
    for (int p = 0; p < 8; p++) {
      int n = p * 32 + nn;
      half4 h;
      #pragma unroll
      for (int i = 0; i < 4; i++) h[i] = T[c + i][n];
      *(half4*)(D + (long)n * 32 + c) = h;
    }
  }
}

// ---------------- transpose f16: Yf [384][1024] -> Yt [12][1024][32] per b --------
__launch_bounds__(256)
__global__ void k_trh(const _Float16* __restrict__ src, _Float16* __restrict__ dst) {
  const int cblk = blockIdx.x, nseg = blockIdx.y, b = blockIdx.z;
  const _Float16* S = src + ((long)b * 384 + cblk * 32) * 1024 + nseg * 256;
  _Float16* D = dst + (long)b * 393216 + cblk * 32768 + (long)nseg * 256 * 32;
  __shared__ _Float16 T[32][264];
  const int wv = threadIdx.x >> 6, lane = threadIdx.x & 63;
  #pragma unroll
  for (int rr = 0; rr < 8; rr++) {
    int r = wv * 8 + rr;
    *(half4*)&T[r][lane * 4] = *(const half4*)(S + (long)r * 1024 + lane * 4);
  }
  __syncthreads();
  const int nn = threadIdx.x >> 3, c = (threadIdx.x & 7) * 4;
  #pragma unroll
  for (int p = 0; p < 8; p++) {
    int n = p * 32 + nn;
    half4 h;
    #pragma unroll
    for (int i = 0; i < 4; i++) h[i] = T[c + i][n];
    *(half4*)(D + (long)n * 32 + c) = h;
  }
}

// ---------------- QKV GEMM: Wf @ Xt per batch -> swizzled Q/K/V + GN partials -----
__launch_bounds__(256, 4)
__global__ void k_qkv(const _Float16* __restrict__ Xt, const _Float16* __restrict__ Wf,
                      _Float16* __restrict__ Qs, _Float16* __restrict__ Ks,
                      _Float16* __restrict__ Vs, float* __restrict__ gnpart) {
  const int tid = threadIdx.x;
  const int lane = tid & 63;
  const int wv = tid >> 6;
  const int l15 = lane & 15;
  const int g = lane >> 4;
  const int o0 = blockIdx.x * 48;
  const int n0 = blockIdx.y * 64;
  const int b = blockIdx.z;

  __shared__ __align__(16) _Float16 WA[18432];   // 36KB: A frags; aliased as T later
  __shared__ float red[8];

  {
    const _Float16* wsrc = Wf + ((long)blockIdx.x * 36 + wv * 9) * 512 + lane * 8;
    uint4 wtmp[9];
    #pragma unroll
    for (int k = 0; k < 9; k++) wtmp[k] = *(const uint4*)(wsrc + k * 512);
    #pragma unroll
    for (int k = 0; k < 9; k++) *(uint4*)(&WA[(wv * 9 + k) * 512 + lane * 8]) = wtmp[k];
  }

  const int ncol = n0 + wv * 16 + l15;
  const _Float16* xp = Xt + (long)b * 393216 + (long)ncol * 32 + g * 8;
  half8 xb[12];
  #pragma unroll
  for (int cb = 0; cb < 12; cb++) xb[cb] = *(const half8*)(xp + cb * 32768);

  __syncthreads();

  floatx4 zero4 = {0.f, 0.f, 0.f, 0.f};
  floatx4 acc0 = zero4, acc1 = zero4, acc2 = zero4;

  #pragma unroll
  for (int cb = 0; cb < 12; cb++) {
    half8 a0 = *(const half8*)&WA[(cb) * 512 + lane * 8];
    half8 a1 = *(const half8*)&WA[(12 + cb) * 512 + lane * 8];
    half8 a2 = *(const half8*)&WA[(24 + cb) * 512 + lane * 8];
    acc0 = __builtin_amdgcn_mfma_f32_16x16x32_f16(a0, xb[cb], acc0, 0, 0, 0);
    acc1 = __builtin_amdgcn_mfma_f32_16x16x32_f16(a1, xb[cb], acc1, 0, 0, 0);
    acc2 = __builtin_amdgcn_mfma_f32_16x16x32_f16(a2, xb[cb], acc2, 0, 0, 0);
  }

  floatx4 acc[3] = {acc0, acc1, acc2};
  __syncthreads();
  _Float16* T = WA;

  if (o0 < 768) {
    #pragma unroll
    for (int rt = 0; rt < 3; rt++)
      #pragma unroll
      for (int r = 0; r < 4; r++)
        T[(wv * 16 + l15) * 52 + rt * 16 + g * 4 + r] = (_Float16)acc[rt][r];
    __syncthreads();
    const int qk = o0 >= 384;
    const int hh = (o0 - qk * 384) / 48;
    _Float16* base = (qk ? Ks : Qs) + (long)(b * 8 + hh) * 65536;
    #pragma unroll
    for (int it = 0; it < 2; it++) {
      int slot = it * 256 + tid;
      int ntl = slot >> 8;
      int t   = (slot >> 6) & 3;
      int ln  = slot & 63;
      int hi_s = ln >> 5, l31_s = ln & 31;
      int n_ = ntl * 32 + l31_s;
      int c0 = t * 16 + hi_s * 8;
      half8 val;
      #pragma unroll
      for (int j = 0; j < 8; j++) {
        int col = c0 + j;
        int d48 = col < 24 ? col : col - 8;
        bool isq = (col < 24) || (col >= 32 && col < 56);
        val[j] = isq ? T[n_ * 52 + d48] : (_Float16)0;
      }
      *(half8*)(base + ((((n0 >> 5) + ntl) * 4 + t) * 64 + ln) * 8) = val;
    }
    if (!qk) {
      float s1 = 0.f, s2 = 0.f;
      int n_ = tid >> 2, k0 = (tid & 3) * 6;
      #pragma unroll
      for (int k = 0; k < 6; k++) {
        float v = (float)T[n_ * 52 + 24 + k0 + k];
        s1 += v; s2 += v * v;
      }
      #pragma unroll
      for (int off = 32; off > 0; off >>= 1) {
        s1 += __shfl_down(s1, off);
        s2 += __shfl_down(s2, off);
      }
      if ((tid & 63) == 0) { red[tid >> 6] = s1; red[4 + (tid >> 6)] = s2; }
      __syncthreads();
      if (tid == 0) {
        int slot = (b * 8 + hh) * 16 + (n0 >> 6);
        gnpart[slot * 2]     = red[0] + red[1] + red[2] + red[3];
        gnpart[slot * 2 + 1] = red[4] + red[5] + red[6] + red[7];
      }
    }
  } else {
    #pragma unroll
    for (int rt = 0; rt < 3; rt++)
      #pragma unroll
      for (int r = 0; r < 4; r++)
        T[(rt * 16 + g * 4 + r) * 72 + wv * 16 + l15] = (_Float16)acc[rt][r];
    __syncthreads();
    const int hh = (o0 - 768) / 48;
    _Float16* base = Vs + (long)(b * 8 + hh) * 65536;
    #pragma unroll
    for (int it = 0; it < 2; it++) {
      int slot = it * 256 + tid;
      int lwin = slot >> 8;
      int ckc  = (slot >> 6) & 3;
      int kc   = ckc & 1, c = ckc >> 1;
      int ln = slot & 63;
      int hi_s = ln >> 5, l31_s = ln & 31;
      int d48 = c * 32 + l31_s;
      half8 val;
      if (d48 < 48) {
        int mb = lwin * 32 + kc * 16 + hi_s * 4;
        half4 a = *(const half4*)&T[d48 * 72 + mb];
        half4 bq = *(const half4*)&T[d48 * 72 + mb + 8];
        val[0] = a[0]; val[1] = a[1]; val[2] = a[2]; val[3] = a[3];
        val[4] = bq[0]; val[5] = bq[1]; val[6] = bq[2]; val[7] = bq[3];
      } else {
        _Float16 f = (d48 == 48) ? (_Float16)1 : (_Float16)0;
        #pragma unroll
        for (int j = 0; j < 8; j++) val[j] = f;
      }
      *(half8*)(base + ((((n0 >> 5) + lwin) * 4 + ckc) * 64 + ln) * 8) = val;
    }
  }
}

// ---------------- fused dual-softmax attention: both branches per wave -----------
// (round-17 version, verified) Block = 4 waves = 4 ntiles; each wave computes
// BOTH branches. K/V LDS staging 2x16KB dbuf, one barrier per 64-key pair; diff
// in-register; flat f16 Yf write (verified map).
__launch_bounds__(256, 2)
__global__ void k_attn(const _Float16* __restrict__ Qs, const _Float16* __restrict__ Ks,
                       const _Float16* __restrict__ Vs, const float* __restrict__ gnpart,
                       const float* __restrict__ lam, const float* __restrict__ gw,
                       const float* __restrict__ gb, _Float16* __restrict__ Yf) {
  const int tid = threadIdx.x;
  const int lane = tid & 63;
  const int wv = tid >> 6;          // 0..3 = ntile within group
  const int l31 = lane & 31;
  const int hi = lane >> 5;
  const int id = blockIdx.x;
  const int bh = ((id >> 6) << 3) | (id & 7);
  const int ntlgrp = (id >> 3) & 7;
  const int ntile = ntlgrp * 4 + wv;
  const int n0 = ntile * 32;
  const int b = bh >> 3, h = bh & 7;

  const _Float16* Qp = Qs + (long)bh * 65536 + (ntile * 256 + lane) * 8;
  half8 qr0a = *(const half8*)(Qp);
  half8 qr0b = *(const half8*)(Qp + 512);
  half8 qr1a = *(const half8*)(Qp + 1024);
  half8 qr1b = *(const half8*)(Qp + 1536);
  half8 qf0a, qf0b, qf1a, qf1b;
  {
    const float s1s = SCALE * LOG2E;
    #pragma unroll
    for (int j = 0; j < 8; j++) {
      qf0a[j] = (_Float16)((float)qr0a[j] * s1s);
      qf0b[j] = (_Float16)((float)qr0b[j] * s1s);
    }
    const int grp = h >> 2;
    const float* pp = gnpart + (b * 128 + grp * 64) * 2;
    float S1 = pp[lane * 2], S2 = pp[lane * 2 + 1];
    #pragma unroll
    for (int off = 1; off < 64; off <<= 1) {
      S1 += __shfl_xor(S1, off);
      S2 += __shfl_xor(S2, off);
    }
    float mean = S1 * (1.f / 98304.f);
    float rstd = rsqrtf(S2 * (1.f / 98304.f) - mean * mean + 1e-5f);
    float sl = s1s * lam[h];
    const float* gwp = gw + h * 24;
    const float* gbp = gb + h * 24;
    #pragma unroll
    for (int j = 0; j < 8; j++) {
      qf1a[j] = (_Float16)((((float)qr1a[j] - mean) * rstd * gwp[hi * 8 + j] + gbp[hi * 8 + j]) * sl);
      qf1b[j] = (_Float16)((((float)qr1b[j] - mean) * rstd * gwp[16 + j] + gbp[16 + j]) * sl);
    }
  }

  const _Float16* gK = Ks + (long)bh * 65536 + wv * 1024 + lane * 8;
  const _Float16* gV = Vs + (long)bh * 65536 + wv * 1024 + lane * 8;

  __shared__ __align__(16) char smem[32768];   // [2 bufs][K 8KB | V 8KB]
  const int ldsK0 = wv * 2048 + lane * 16;
  const int ldsV0 = 8192 + wv * 2048 + lane * 16;

  floatx16 z16;
  #pragma unroll
  for (int i = 0; i < 16; i++) z16[i] = 0.f;
  floatx16 acc1A = z16, acc1B = z16, acc2A = z16, acc2B = z16;

  {
    uint4 k0 = *(const uint4*)gK;
    uint4 k1 = *(const uint4*)(gK + 512);
    uint4 v0 = *(const uint4*)gV;
    uint4 v1 = *(const uint4*)(gV + 512);
    *(uint4*)(smem + ldsK0) = k0;
    *(uint4*)(smem + ldsK0 + 1024) = k1;
    *(uint4*)(smem + ldsV0) = v0;
    *(uint4*)(smem + ldsV0 + 1024) = v1;
  }
  __syncthreads();

  #pragma unroll 2
  for (int i = 0; i < 16; i++) {
    const int cur = (i & 1) << 14;
    uint4 sk0, sk1, sv0, sv1;
    if (i < 15) {
      sk0 = *(const uint4*)(gK + (i + 1) * 4096);
      sk1 = *(const uint4*)(gK + (i + 1) * 4096 + 512);
      sv0 = *(const uint4*)(gV + (i + 1) * 4096);
      sv1 = *(const uint4*)(gV + (i + 1) * 4096 + 512);
    }
    #pragma unroll
    for (int j = 0; j < 2; j++) {
      const char* Kb = smem + cur + j * 4096;
      const char* Vb = smem + cur + 8192 + j * 4096;
      half8 kf0a = *(const half8*)(Kb + lane * 16);
      half8 kf0b = *(const half8*)(Kb + 1024 + lane * 16);
      half8 kf1a = *(const half8*)(Kb + 2048 + lane * 16);
      half8 kf1b = *(const half8*)(Kb + 3072 + lane * 16);

      floatx16 s1 = __builtin_amdgcn_mfma_f32_32x32x16_f16(kf0a, qf0a, z16, 0, 0, 0);
      s1 = __builtin_amdgcn_mfma_f32_32x32x16_f16(kf0b, qf0b, s1, 0, 0, 0);
      floatx16 s2 = __builtin_amdgcn_mfma_f32_32x32x16_f16(kf1a, qf1a, z16, 0, 0, 0);
      s2 = __builtin_amdgcn_mfma_f32_32x32x16_f16(kf1b, qf1b, s2, 0, 0, 0);

      half8 vf0 = *(const half8*)(Vb + lane * 16);
      half8 vf1 = *(const half8*)(Vb + 1024 + lane * 16);
      half8 vf2 = *(const half8*)(Vb + 2048 + lane * 16);
      half8 vf3 = *(const half8*)(Vb + 3072 + lane * 16);

      uint32_t u1[8], u2[8];
      #pragma unroll
      for (int q = 0; q < 8; q++) {
        u1[q] = pkrtz(fexp2(s1[2 * q]), fexp2(s1[2 * q + 1]));
        u2[q] = pkrtz(fexp2(s2[2 * q]), fexp2(s2[2 * q + 1]));
      }

      union { uint32_t u[4]; half8 h; } pa;
      pa.u[0] = u1[0]; pa.u[1] = u1[1]; pa.u[2] = u1[2]; pa.u[3] = u1[3];
      half8 p1c0 = pa.h;
      pa.u[0] = u1[4]; pa.u[1] = u1[5]; pa.u[2] = u1[6]; pa.u[3] = u1[7];
      half8 p1c1 = pa.h;
      pa.u[0] = u2[0]; pa.u[1] = u2[1]; pa.u[2] = u2[2]; pa.u[3] = u2[3];
      half8 p2c0 = pa.h;
      pa.u[0] = u2[4]; pa.u[1] = u2[5]; pa.u[2] = u2[6]; pa.u[3] = u2[7];
      half8 p2c1 = pa.h;

      acc1A = __builtin_amdgcn_mfma_f32_32x32x16_f16(p1c0, vf0, acc1A, 0, 0, 0);
      acc1A = __builtin_amdgcn_mfma_f32_32x32x16_f16(p1c1, vf1, acc1A, 0, 0, 0);
      acc1B = __builtin_amdgcn_mfma_f32_32x32x16_f16(p1c0, vf2, acc1B, 0, 0, 0);
      acc1B = __builtin_amdgcn_mfma_f32_32x32x16_f16(p1c1, vf3, acc1B, 0, 0, 0);
      acc2A = __builtin_amdgcn_mfma_f32_32x32x16_f16(p2c0, vf0, acc2A, 0, 0, 0);
      acc2A = __builtin_amdgcn_mfma_f32_32x32x16_f16(p2c1, vf1, acc2A, 0, 0, 0);
      acc2B = __builtin_amdgcn_mfma_f32_32x32x16_f16(p2c0, vf2, acc2B, 0, 0, 0);
      acc2B = __builtin_amdgcn_mfma_f32_32x32x16_f16(p2c1, vf3, acc2B, 0, 0, 0);
    }
    if (i < 15) {
      const int nxt = cur ^ 16384;
      *(uint4*)(smem + nxt + ldsK0) = sk0;
      *(uint4*)(smem + nxt + ldsK0 + 1024) = sk1;
      *(uint4*)(smem + nxt + ldsV0) = sv0;
      *(uint4*)(smem + nxt + ldsV0 + 1024) = sv1;
    }
    __syncthreads();
  }

  {
    _Float16* Ybh = Yf + (long)bh * 49152;
    const int src = (lane & 32) + 16;
    #pragma unroll
    for (int r = 0; r < 16; r++) {
      float i1 = __builtin_amdgcn_rcpf(__shfl(acc1B[r], src));
      float i2 = __builtin_amdgcn_rcpf(__shfl(acc2B[r], src));
      int n = n0 + (r & 3) + 8 * ((r >> 2) & 3) + 4 * hi;
      float o0 = acc1A[r] * i1 - acc2A[r] * i2;   // d = l31
      float o1 = acc1B[r] * i1 - acc2B[r] * i2;   // d = 32 + l31 (valid < 48)
      int p0 = l31 >= 24;
      Ybh[p0 * 24576 + n * 24 + (l31 - p0 * 24)] = (_Float16)o0;
      if (l31 < 16) Ybh[24576 + n * 24 + 8 + l31] = (_Float16)o1;
    }
  }
}

// ---------------- proj GEMM: PWf @ Yt + b (A staged in LDS) ----------------
__launch_bounds__(256, 4)
__global__ void k_proj(const _Float16* __restrict__ Yt, const _Float16* __restrict__ PWf,
                       const float* __restrict__ PB, float* __restrict__ out) {
  const int tid = threadIdx.x, lane = tid & 63, wv = tid >> 6, l15 = lane & 15, g = lane >> 4;
  const int o0 = blockIdx.x * 64, m0 = blockIdx.y * 64, b = blockIdx.z;

  __shared__ __align__(16) _Float16 PA[24576];   // 48KB: 48 A frags

  {
    const _Float16* psrc = PWf + ((long)blockIdx.x * 48 + wv * 12) * 512 + lane * 8;
    uint4 ptmp[12];
    #pragma unroll
    for (int k = 0; k < 12; k++) ptmp[k] = *(const uint4*)(psrc + k * 512);
    #pragma unroll
    for (int k = 0; k < 12; k++) *(uint4*)(&PA[(wv * 12 + k) * 512 + lane * 8]) = ptmp[k];
  }

  const int mcol = m0 + wv * 16 + l15;
  const _Float16* yp = Yt + (long)b * 393216 + (long)mcol * 32 + g * 8;
  half8 yb[12];
  #pragma unroll
  for (int cb = 0; cb < 12; cb++) yb[cb] = *(const half8*)(yp + cb * 32768);

  __syncthreads();

  floatx4 zero4 = {0.f, 0.f, 0.f, 0.f};
  floatx4 acc0 = zero4, acc1 = zero4, acc2 = zero4, acc3 = zero4;

  #pragma unroll
  for (int cb = 0; cb < 12; cb++) {
    half8 a0 = *(const half8*)&PA[(cb) * 512 + lane * 8];
    half8 a1 = *(const half8*)&PA[(12 + cb) * 512 + lane * 8];
    half8 a2 = *(const half8*)&PA[(24 + cb) * 512 + lane * 8];
    half8 a3 = *(const half8*)&PA[(36 + cb) * 512 + lane * 8];
    acc0 = __builtin_amdgcn_mfma_f32_16x16x32_f16(a0, yb[cb], acc0, 0, 0, 0);
    acc1 = __builtin_amdgcn_mfma_f32_16x16x32_f16(a1, yb[cb], acc1, 0, 0, 0);
    acc2 = __builtin_amdgcn_mfma_f32_16x16x32_f16(a2, yb[cb], acc2, 0, 0, 0);
    acc3 = __builtin_amdgcn_mfma_f32_16x16x32_f16(a3, yb[cb], acc3, 0, 0, 0);
  }

  floatx4 acc[4] = {acc0, acc1, acc2, acc3};
  #pragma unroll
  for (int rt = 0; rt < 4; rt++) {
    int o_ = o0 + rt * 16 + g * 4;
    #pragma unroll
    for (int r = 0; r < 4; r++) {
      out[(long)(b * 384 + o_ + r) * 1024 + mcol] = acc[rt][r] + PB[o_ + r];
    }
  }
}

extern "C" void kernel_launch(void* const* d_in, const int* in_sizes, int n_in,
                              void* d_out, int out_size, void* d_ws, size_t ws_size,
                              hipStream_t stream) {
  const float* x     = (const float*)d_in[0];
  const float* qkv_w = (const float*)d_in[1];
  const float* lam   = (const float*)d_in[2];
  const float* gw    = (const float*)d_in[3];
  const float* gb    = (const float*)d_in[4];
  const float* pw    = (const float*)d_in[5];
  const float* pb    = (const float*)d_in[6];
  float* out = (float*)d_out;
  char* ws = (char*)d_ws;
  _Float16* Qs  = (_Float16*)ws;
  _Float16* Ks  = (_Float16*)(ws + 8388608);
  _Float16* Vs  = (_Float16*)(ws + 16777216);
  float* gnpart   = (float*)(ws + 25165824);
  _Float16* Yf  = (_Float16*)(ws + 26214400);
  _Float16* Xt  = (_Float16*)(ws + 37752832);
  _Float16* Yt  = (_Float16*)(ws + 44044288);
  _Float16* Wf  = (_Float16*)(ws + 50335744);
  _Float16* PWf = (_Float16*)(ws + 51220480);

  hipLaunchKernelGGL(k_prep,    dim3(672),        dim3(256), 0, stream, qkv_w, pw, x, Wf, PWf, Xt);
  hipLaunchKernelGGL(k_qkv,     dim3(24, 16, 8),  dim3(256), 0, stream, Xt, Wf, Qs, Ks, Vs, gnpart);
  hipLaunchKernelGGL(k_attn,    dim3(512),        dim3(256), 0, stream, Qs, Ks, Vs, gnpart, lam, gw, gb, Yf);
  hipLaunchKernelGGL(k_trh,     dim3(12, 4, 8),   dim3(256), 0, stream, Yf, Yt);
  hipLaunchKernelGGL(k_proj,    dim3(6, 16, 8),   dim3(256), 0, stream, Yt, PWf, pb, out);
}